// Round 6
// baseline (20.155 us; speedup 1.0000x reference)
//
#include <hip/hip_runtime.h>
#include <math.h>

#define BB 8
#define HH 256
#define WW 256
#define PAD 16
#define LDSW (WW + 2 * PAD + 4)   // 292: +4 so field rows land on offset banks
#define NROW (BB * HH)

// Workspace layout (all slots written unconditionally every call -> no
// memset node in the graph):
//   colbits : BB*WW*32 u8   = 65536 B   (byte w covers rows 8w..8w+7; little-
//                                        endian => u64 word k = rows 64k..64k+63)
//   blockany: BB*32   int   =  1024 B
//   partial : NROW    double= 16384 B

// ---------------------------------------------------------------------------
// Kernel A: per-column occupancy bitmasks, 8 rows per block -> u8 words.
// Grid (BB, 32) = 256 blocks, 256 threads (one per column j). Coalesced reads.
// ---------------------------------------------------------------------------
__global__ void build_colbits_kernel(const int* __restrict__ targets,
                                     unsigned char* __restrict__ colbits,
                                     int* __restrict__ blockany) {
    const int b = blockIdx.x;
    const int w = blockIdx.y;          // 0..31
    const int j = threadIdx.x;         // 0..255
    const int* t = targets + ((size_t)b * HH + 8 * w) * WW + j;
    unsigned int bits = 0u;
    #pragma unroll
    for (int r = 0; r < 8; ++r)
        bits |= (unsigned int)(t[r * WW] != 0) << r;
    colbits[((size_t)(b * WW + j) << 5) + w] = (unsigned char)bits;

    __shared__ int anyw[4];
    const unsigned long long ba = __ballot(bits != 0u);
    if ((j & 63) == 0) anyw[j >> 6] = (ba != 0ull) ? 1 : 0;
    __syncthreads();
    if (j == 0)
        blockany[b * 32 + w] = anyw[0] | anyw[1] | anyw[2] | anyw[3];
}

// ---------------------------------------------------------------------------
// Vertical 1D distance to nearest SET bit in the 256-bit column word, exact
// reference scan semantics: d(i) = min(i - prev_set, next_set - i, i+513, 768-i).
// ---------------------------------------------------------------------------
__device__ __forceinline__ float col_dist(unsigned long long w0, unsigned long long w1,
                                          unsigned long long w2, unsigned long long w3,
                                          int i) {
    const int INF = 1 << 20;
    int best = min(i + 513, 768 - i);
    const unsigned long long ws[4] = {w0, w1, w2, w3};
    #pragma unroll
    for (int k = 0; k < 4; ++k) {
        const unsigned long long wk = ws[k];
        const int rel = i - 64 * k;
        {
            const int sh = min(max(rel, 0), 63);
            const unsigned long long m = (rel < 64) ? (wk >> sh) : 0ull;
            const int d = m ? (__ffsll((unsigned long long)m) - 1 + sh - rel) : INF;
            best = min(best, d);
        }
        {
            const int sh = min(max(63 - rel, 0), 63);
            const unsigned long long m = (rel >= 0) ? (wk << sh) : 0ull;
            const int add = rel > 63 ? rel - 63 : 0;
            const int d = m ? (__clzll((long long)m) + add) : INF;
            best = min(best, d);
        }
    }
    return (float)best;
}

// ---------------------------------------------------------------------------
// Kernel B: one block per row (b, i), 256 threads (one per column j).
// Identity: per column, g_out = m ? 0 : d and g_in = m ? d : 0 where d is the
// 1D distance to the nearest OPPOSITE-polarity bit -> ONE col_dist call on
// XOR-inverted words. Each pixel then scans only its needed field with an
// exact block-uniform tiered window: argmin l* obeys (j-l*)^2 <= d2[j] <=
// h[j]=d^2 <= hmax, so hmax<=100 -> +-10 window; hmax<=288 -> +-16; else full.
// All tiers fully unrolled; pads hold 1e30.
// ---------------------------------------------------------------------------
__global__ void fused_row_kernel(const float* __restrict__ logits,
                                 const unsigned char* __restrict__ colbits,
                                 double* __restrict__ partial) {
    const int row = blockIdx.x;        // b*HH + i
    const int b = row >> 8;
    const int i = row & 255;
    const int j = threadIdx.x;
    const int lane = j & 63;
    const int wid  = j >> 6;

    __shared__ __align__(16) float sbuf[2][LDSW];   // [0]=out field, [1]=in field
    __shared__ float hred[4];
    __shared__ double wsum[4];

    const ulonglong2* cb =
        (const ulonglong2*)(colbits + ((size_t)(b * WW + j) << 5));
    const ulonglong2 lo = cb[0], hi = cb[1];
    const unsigned long long w0 = lo.x, w1 = lo.y, w2 = hi.x, w3 = hi.y;
    const float x = logits[(size_t)row * WW + j];   // issue early

    const unsigned long long wsel = (i < 64) ? w0 : (i < 128) ? w1 : (i < 192) ? w2 : w3;
    const bool m = ((wsel >> (i & 63)) & 1ull) != 0ull;

    const unsigned long long inv = m ? ~0ull : 0ull;      // branchless polarity flip
    const float d = col_dist(w0 ^ inv, w1 ^ inv, w2 ^ inv, w3 ^ inv, i);
    const float d2v = d * d;                              // exact integer in f32

    sbuf[0][PAD + j] = m ? 0.0f : d2v;    // g_out^2
    sbuf[1][PAD + j] = m ? d2v : 0.0f;    // g_in^2
    if (j < PAD) {
        sbuf[0][j] = 1e30f;            sbuf[1][j] = 1e30f;
        sbuf[0][PAD + WW + j] = 1e30f; sbuf[1][PAD + WW + j] = 1e30f;
    }

    // hmax = max over row of per-pixel ceiling h = d^2
    float hmax = d2v;
    #pragma unroll
    for (int off = 32; off > 0; off >>= 1)
        hmax = fmaxf(hmax, __shfl_xor(hmax, off, 64));
    if (lane == 0) hred[wid] = hmax;
    __syncthreads();                   // covers sbuf + pads + hred
    hmax = fmaxf(fmaxf(hred[0], hred[1]), fmaxf(hred[2], hred[3]));

    const float* s = &sbuf[m ? 1 : 0][PAD];
    float d2 = 1e30f;
    if (hmax <= 100.0f) {              // exact: |j - argmin| <= 10
        const float* sw = s + j - 10;
        float df = 10.0f;
        #pragma unroll
        for (int k = 0; k <= 20; ++k) {
            d2 = fminf(d2, fmaf(df, df, sw[k]));
            df -= 1.0f;
        }
    } else if (hmax <= 288.0f) {       // exact: |j - argmin| <= 16
        const float* sw = s + j - PAD;
        float df = (float)PAD;
        #pragma unroll
        for (int k = 0; k <= 2 * PAD; ++k) {
            d2 = fminf(d2, fmaf(df, df, sw[k]));
            df -= 1.0f;
        }
    } else {                           // uniform fallback: full exact scan
        float df = (float)j;
        #pragma unroll 8
        for (int l = 0; l < WW; ++l) {
            d2 = fminf(d2, fmaf(df, df, s[l]));
            df -= 1.0f;
        }
    }

    const double sd = sqrt((double)d2);
    const double sdf = m ? -sd : sd;                // dist_out - dist_in
    const double p  = 1.0 / (1.0 + exp(-(double)x));
    double c = p * sdf;

    #pragma unroll
    for (int off = 32; off > 0; off >>= 1)
        c += __shfl_down(c, off, 64);
    if (lane == 0) wsum[wid] = c;
    __syncthreads();
    if (j == 0)
        partial[row] = wsum[0] + wsum[1] + wsum[2] + wsum[3];   // no atomics
}

// ---------------------------------------------------------------------------
// Kernel C: finalize. 1 block x 256 threads; thread t sums partial[b*256+t]
// gated by batch-any flag; shuffle+LDS reduce; single write to out.
// ---------------------------------------------------------------------------
__global__ void finalize_kernel(const double* __restrict__ partial,
                                const int* __restrict__ blockany,
                                float* __restrict__ out) {
    const int t = threadIdx.x;         // 0..255
    double s = 0.0;
    #pragma unroll
    for (int b = 0; b < BB; ++b) {
        int f = 0;
        #pragma unroll
        for (int w = 0; w < 32; ++w) f |= blockany[b * 32 + w];
        const double v = partial[b * HH + t];
        s += f ? v : 0.0;
    }
    #pragma unroll
    for (int off = 32; off > 0; off >>= 1)
        s += __shfl_down(s, off, 64);
    __shared__ double wsum[4];
    if ((t & 63) == 0) wsum[t >> 6] = s;
    __syncthreads();
    if (t == 0)
        out[0] = (float)((wsum[0] + wsum[1] + wsum[2] + wsum[3])
                         / (double)((long long)BB * HH * WW));
}

extern "C" void kernel_launch(void* const* d_in, const int* in_sizes, int n_in,
                              void* d_out, int out_size, void* d_ws, size_t ws_size,
                              hipStream_t stream) {
    const float* logits  = (const float*)d_in[0];
    const int*   targets = (const int*)d_in[1];
    float*       out     = (float*)d_out;

    char* ws = (char*)d_ws;
    const size_t off_bits = 0;                                    // 64 KB
    const size_t off_any  = (size_t)BB * WW * 32;                 // u8 bytes
    const size_t off_par  = off_any + (size_t)BB * 32 * sizeof(int);

    unsigned char* colbits  = (unsigned char*)(ws + off_bits);
    int*           blockany = (int*)(ws + off_any);
    double*        partial  = (double*)(ws + off_par);

    build_colbits_kernel<<<dim3(BB, 32), WW, 0, stream>>>(targets, colbits, blockany);
    fused_row_kernel<<<NROW, WW, 0, stream>>>(logits, colbits, partial);
    finalize_kernel<<<1, WW, 0, stream>>>(partial, blockany, out);
}

// Round 7
// 17.367 us; speedup vs baseline: 1.1606x; 1.1606x over previous
//
#include <hip/hip_runtime.h>
#include <math.h>

#define BB 8
#define HH 256
#define WW 256
#define PAD 16
#define LDSW (WW + 2 * PAD + 4)   // 292: +4 so the two field rows offset banks
#define NROW (BB * HH)

// Workspace layout (all slots written unconditionally every call -> no
// memset node in the graph):
//   colbits : BB*WW*8 u32   = 65536 B   (u32 word w covers rows 32w..32w+31)
//   blockany: BB*8    int   =   256 B
//   partial : NROW    double= 16384 B

// ---------------------------------------------------------------------------
// Kernel A: per-column occupancy bitmasks, 32 rows per block -> u32 words.
// Grid (BB, 8) = 64 blocks, 256 threads (one per column j). Coalesced reads.
// ---------------------------------------------------------------------------
__global__ void build_colbits_kernel(const int* __restrict__ targets,
                                     unsigned int* __restrict__ colbits,
                                     int* __restrict__ blockany) {
    const int b = blockIdx.x;
    const int w = blockIdx.y;          // 0..7
    const int j = threadIdx.x;         // 0..255
    const int* t = targets + ((size_t)b * HH + 32 * w) * WW + j;
    unsigned int bits = 0u;
    #pragma unroll
    for (int r = 0; r < 32; ++r)
        bits |= (unsigned int)(t[r * WW] != 0) << r;
    colbits[((size_t)(b * WW + j) << 3) + w] = bits;

    __shared__ int anyw[4];
    const unsigned long long ba = __ballot(bits != 0u);
    if ((j & 63) == 0) anyw[j >> 6] = (ba != 0ull) ? 1 : 0;
    __syncthreads();
    if (j == 0)
        blockany[b * 8 + w] = anyw[0] | anyw[1] | anyw[2] | anyw[3];
}

// ---------------------------------------------------------------------------
// Vertical 1D distance to nearest SET bit in the 256-bit column word, exact
// reference scan semantics: d(i) = min(i - prev_set, next_set - i, i+513, 768-i).
// i is block-uniform -> shifts are SALU; k is compile-time.
// ---------------------------------------------------------------------------
__device__ __forceinline__ float col_dist(unsigned long long w0, unsigned long long w1,
                                          unsigned long long w2, unsigned long long w3,
                                          int i) {
    const int INF = 1 << 20;
    int best = min(i + 513, 768 - i);
    const unsigned long long ws[4] = {w0, w1, w2, w3};
    #pragma unroll
    for (int k = 0; k < 4; ++k) {
        const unsigned long long wk = ws[k];
        const int rel = i - 64 * k;
        {
            const int sh = min(max(rel, 0), 63);
            const unsigned long long m = (rel < 64) ? (wk >> sh) : 0ull;
            const int d = m ? (__ffsll((unsigned long long)m) - 1 + sh - rel) : INF;
            best = min(best, d);
        }
        {
            const int sh = min(max(63 - rel, 0), 63);
            const unsigned long long m = (rel >= 0) ? (wk << sh) : 0ull;
            const int add = rel > 63 ? rel - 63 : 0;
            const int d = m ? (__clzll((long long)m) + add) : INF;
            best = min(best, d);
        }
    }
    return (float)best;
}

// ---------------------------------------------------------------------------
// Kernel B: one block per row (b, i), 256 threads (one per column j).
// Identity: g_out[l] = m_l ? 0 : d_l, g_in[l] = m_l ? d_l : 0, where d_l is
// the 1D distance to the nearest OPPOSITE-polarity bit -> ONE col_dist on
// XOR-inverted words. Pixel j scans only its needed field. Exact window:
// the l=j candidate gives d2[j] <= d_j^2, so (j-l*)^2 <= wave-max(d^2); if
// that max <= 288 the fully-unrolled +-16 window provably contains the
// argmin (wave-uniform branch); else full 256-scan fallback. Pads hold 1e30.
// ---------------------------------------------------------------------------
__global__ void fused_row_kernel(const float* __restrict__ logits,
                                 const unsigned int* __restrict__ colbits,
                                 double* __restrict__ partial) {
    const int row = blockIdx.x;        // b*HH + i
    const int b = row >> 8;
    const int i = row & 255;
    const int j = threadIdx.x;
    const int lane = j & 63;
    const int wid  = j >> 6;

    __shared__ __align__(16) float sbuf[2][LDSW];   // [0]=out field, [1]=in field
    __shared__ double wsum[4];

    const ulonglong2* cb =
        (const ulonglong2*)(colbits + ((size_t)(b * WW + j) << 3));
    const ulonglong2 lo = cb[0], hi = cb[1];
    const unsigned long long w0 = lo.x, w1 = lo.y, w2 = hi.x, w3 = hi.y;
    const float x = logits[(size_t)row * WW + j];   // issue early

    const unsigned long long wsel = (i < 64) ? w0 : (i < 128) ? w1 : (i < 192) ? w2 : w3;
    const bool m = ((wsel >> (i & 63)) & 1ull) != 0ull;

    const unsigned long long inv = m ? ~0ull : 0ull;      // branchless polarity flip
    const float d = col_dist(w0 ^ inv, w1 ^ inv, w2 ^ inv, w3 ^ inv, i);
    const float d2v = d * d;                              // exact integer in f32

    sbuf[0][PAD + j] = m ? 0.0f : d2v;    // g_out^2
    sbuf[1][PAD + j] = m ? d2v : 0.0f;    // g_in^2
    if (j < PAD) {
        sbuf[0][j] = 1e30f;            sbuf[1][j] = 1e30f;
        sbuf[0][PAD + WW + j] = 1e30f; sbuf[1][PAD + WW + j] = 1e30f;
    }

    // wave-level ceiling: valid per-pixel bound, wave-uniform branch
    float hmax = d2v;
    #pragma unroll
    for (int off = 32; off > 0; off >>= 1)
        hmax = fmaxf(hmax, __shfl_xor(hmax, off, 64));
    __syncthreads();                   // sbuf + pads visible to all waves

    const float* s = &sbuf[m ? 1 : 0][PAD];
    float d2 = 1e30f;
    if (hmax <= 288.0f) {              // exact: |j - argmin| <= 16 for this wave
        const float* sw = s + j - PAD;
        float df = (float)PAD;
        #pragma unroll
        for (int k = 0; k <= 2 * PAD; ++k) {
            d2 = fminf(d2, fmaf(df, df, sw[k]));
            df -= 1.0f;
        }
    } else {                           // uniform fallback: full exact scan
        float df = (float)j;
        #pragma unroll 8
        for (int l = 0; l < WW; ++l) {
            d2 = fminf(d2, fmaf(df, df, s[l]));
            df -= 1.0f;
        }
    }

    const double sd = sqrt((double)d2);
    const double sdf = m ? -sd : sd;                // dist_out - dist_in
    const float  pf = __fdividef(1.0f, 1.0f + __expf(-x));   // f32 sigmoid
    double c = (double)pf * sdf;

    #pragma unroll
    for (int off = 32; off > 0; off >>= 1)
        c += __shfl_down(c, off, 64);
    if (lane == 0) wsum[wid] = c;
    __syncthreads();
    if (j == 0)
        partial[row] = wsum[0] + wsum[1] + wsum[2] + wsum[3];   // no atomics
}

// ---------------------------------------------------------------------------
// Kernel C: finalize. 1 block x 256 threads; thread t sums partial[b*256+t]
// gated by batch-any flag; shuffle+LDS reduce; single write to out.
// ---------------------------------------------------------------------------
__global__ void finalize_kernel(const double* __restrict__ partial,
                                const int* __restrict__ blockany,
                                float* __restrict__ out) {
    const int t = threadIdx.x;         // 0..255
    double s = 0.0;
    #pragma unroll
    for (int b = 0; b < BB; ++b) {
        int f = 0;
        #pragma unroll
        for (int w = 0; w < 8; ++w) f |= blockany[b * 8 + w];
        const double v = partial[b * HH + t];
        s += f ? v : 0.0;
    }
    #pragma unroll
    for (int off = 32; off > 0; off >>= 1)
        s += __shfl_down(s, off, 64);
    __shared__ double wsum[4];
    if ((t & 63) == 0) wsum[t >> 6] = s;
    __syncthreads();
    if (t == 0)
        out[0] = (float)((wsum[0] + wsum[1] + wsum[2] + wsum[3])
                         / (double)((long long)BB * HH * WW));
}

extern "C" void kernel_launch(void* const* d_in, const int* in_sizes, int n_in,
                              void* d_out, int out_size, void* d_ws, size_t ws_size,
                              hipStream_t stream) {
    const float* logits  = (const float*)d_in[0];
    const int*   targets = (const int*)d_in[1];
    float*       out     = (float*)d_out;

    char* ws = (char*)d_ws;
    const size_t off_bits = 0;                                    // 64 KB
    const size_t off_any  = (size_t)BB * WW * 8 * sizeof(unsigned int);
    const size_t off_par  = off_any + 256;

    unsigned int* colbits  = (unsigned int*)(ws + off_bits);
    int*          blockany = (int*)(ws + off_any);
    double*       partial  = (double*)(ws + off_par);

    build_colbits_kernel<<<dim3(BB, 8), WW, 0, stream>>>(targets, colbits, blockany);
    fused_row_kernel<<<NROW, WW, 0, stream>>>(logits, colbits, partial);
    finalize_kernel<<<1, WW, 0, stream>>>(partial, blockany, out);
}